// Round 2
// baseline (4473.258 us; speedup 1.0000x reference)
//
#include <hip/hip_runtime.h>
#include <hip/hip_bf16.h>

// N=50000 nodes, E=800000 edges, D=96 (in = hidden = out)
#define NNODES 50000
#define NEDGES 800000
#define DIM    96

// ---------- runtime-dtype helpers ----------
// flags[0] = 1 if float tensors are bf16, 0 if f32
// flags[1] = 1 if edge_index is int64, 0 if int32
__device__ __forceinline__ float loadF(const void* p, long i, int isbf) {
    return isbf ? __bfloat162float(((const __hip_bfloat16*)p)[i])
                : ((const float*)p)[i];
}
__device__ __forceinline__ int clampN(int v) {
    return v < 0 ? 0 : (v >= NNODES ? NNODES - 1 : v);
}

// single wave: sniff x's float dtype and edge_index's int width
__global__ void k_sniff(const unsigned* __restrict__ xw,
                        const unsigned* __restrict__ ew,
                        int* __restrict__ flags) {
    int lane = threadIdx.x;          // 0..63
    int bad = 0, nz = 0;
    for (int r = 0; r < 4; ++r) {
        unsigned w  = xw[lane + 64 * r];          // first 256 words of x
        unsigned lo = w & 0xffffu;                // low half as bf16?
        unsigned ex = (lo >> 7) & 0xffu;
        if (!(lo == 0u || (ex >= 90u && ex <= 145u))) bad++;
        unsigned o = ew[2 * (lane + 64 * r) + 1]; // odd words of edge_index
        if (o != 0u) nz++;
    }
    for (int off = 32; off; off >>= 1) {
        bad += __shfl_down(bad, off);
        nz  += __shfl_down(nz,  off);
    }
    if (lane == 0) {
        flags[0] = (bad <= 32) ? 1 : 0;  // few implausible low-halves -> bf16
        flags[1] = (nz  <  4) ? 1 : 0;   // odd words all ~zero -> int64
    }
}

// deg[dst] += 1 per edge (self-loop folded into k_dinv)
__global__ void k_deg(const int* __restrict__ w, float* __restrict__ deg,
                      const int* __restrict__ flags) {
    int e = blockIdx.x * blockDim.x + threadIdx.x;
    if (e >= NEDGES) return;
    int is64 = flags[1];
    int d = is64 ? w[2 * (NEDGES + e)] : w[NEDGES + e];
    atomicAdd(&deg[clampN(d)], 1.0f);
}

__global__ void k_dinv(float* __restrict__ deg) {
    int i = blockIdx.x * blockDim.x + threadIdx.x;
    if (i < NNODES) deg[i] = rsqrtf(deg[i] + 1.0f);   // +1 self loop, deg>=1
}

// g[row,j] = bf16( dinv[row] * sum_k X[row,k]*W[k,j] )
// block = 96 threads (one per column), grid = N rows. Safe in-place (X==g).
__global__ void k_gemm(const void* __restrict__ X, int x_force_bf16,
                       const void* __restrict__ W,
                       const float* __restrict__ dinv,
                       __hip_bfloat16* __restrict__ g,
                       const int* __restrict__ flags) {
    __shared__ float xs[DIM];
    const int row = blockIdx.x;
    const int j   = threadIdx.x;
    const int fbf = flags[0];
    const int xbf = x_force_bf16 ? 1 : fbf;
    xs[j] = loadF(X, (long)row * DIM + j, xbf);
    __syncthreads();
    float acc = 0.f;
#pragma unroll 8
    for (int k = 0; k < DIM; ++k)
        acc += xs[k] * loadF(W, (long)k * DIM + j, fbf);
    g[(long)row * DIM + j] = __float2bfloat16(acc * dinv[row]);
}

// acc[dst, :] += g[src, :]; thread = (edge, 8-column chunk), 16B vector load
__global__ void k_scatter(const int* __restrict__ w,
                          const __hip_bfloat16* __restrict__ g,
                          float* __restrict__ acc,
                          const int* __restrict__ flags) {
    const int Q = DIM / 8;                       // 12 chunks/edge
    int tid = blockIdx.x * blockDim.x + threadIdx.x;
    if (tid >= NEDGES * Q) return;               // 9.6M threads
    int is64 = flags[1];
    int e = tid / Q;
    int q = tid - e * Q;
    int s = is64 ? w[2 * e]            : w[e];
    int d = is64 ? w[2 * (NEDGES + e)] : w[NEDGES + e];
    s = clampN(s); d = clampN(d);
    float4 f4 = *reinterpret_cast<const float4*>(g + (size_t)s * DIM + q * 8);
    const __hip_bfloat162* h = reinterpret_cast<const __hip_bfloat162*>(&f4);
    float* a = acc + (size_t)d * DIM + q * 8;
#pragma unroll
    for (int i = 0; i < 4; ++i) {
        float2 v = __bfloat1622float2(h[i]);
        atomicAdd(a + 2 * i,     v.x);
        atomicAdd(a + 2 * i + 1, v.y);
    }
}

// layer-1 epilogue: act = PReLU(dinv*(acc + g) + b1), in-place over g
__global__ void k_post1(const float* __restrict__ acc,
                        __hip_bfloat16* __restrict__ g,
                        const float* __restrict__ dinv,
                        const void* __restrict__ b,
                        const void* __restrict__ a1,
                        const int* __restrict__ flags) {
    int tid = blockIdx.x * blockDim.x + threadIdx.x;
    if (tid >= NNODES * DIM) return;
    int fbf = flags[0];
    int row = tid / DIM, j = tid - row * DIM;
    float val = dinv[row] * (acc[tid] + __bfloat162float(g[tid])) + loadF(b, j, fbf);
    float a = loadF(a1, 0, fbf);
    val = val > 0.f ? val : a * val;
    g[tid] = __float2bfloat16(val);
}

// layer-2 epilogue: out = dinv*(acc + g) + b2, stored per sniffed out dtype
__global__ void k_final(const float* __restrict__ acc,
                        const __hip_bfloat16* __restrict__ g,
                        const float* __restrict__ dinv,
                        const void* __restrict__ b,
                        void* __restrict__ out,
                        const int* __restrict__ flags) {
    int tid = blockIdx.x * blockDim.x + threadIdx.x;
    if (tid >= NNODES * DIM) return;
    int fbf = flags[0];
    int row = tid / DIM, j = tid - row * DIM;
    float val = dinv[row] * (acc[tid] + __bfloat162float(g[tid])) + loadF(b, j, fbf);
    if (fbf) ((__hip_bfloat16*)out)[tid] = __float2bfloat16(val);
    else     ((float*)out)[tid] = val;
}

extern "C" void kernel_launch(void* const* d_in, const int* in_sizes, int n_in,
                              void* d_out, int out_size, void* d_ws, size_t ws_size,
                              hipStream_t stream) {
    const void* x  = d_in[0];
    const int*  ei = (const int*)d_in[1];
    const void* W1 = d_in[2];
    const void* b1 = d_in[3];
    const void* a1 = d_in[4];
    const void* W2 = d_in[5];
    const void* b2 = d_in[6];

    // workspace layout (all 256B aligned)
    size_t off = 0;
    auto alloc = [&](size_t bytes) { size_t p = off; off = (off + bytes + 255) & ~(size_t)255; return p; };
    char* ws = (char*)d_ws;
    int*            flags = (int*)           (ws + alloc(1024));
    float*          dinv  = (float*)         (ws + alloc((size_t)NNODES * 4));
    __hip_bfloat16* g     = (__hip_bfloat16*)(ws + alloc((size_t)NNODES * DIM * 2));
    float*          acc   = (float*)         (ws + alloc((size_t)NNODES * DIM * 4));
    if (ws_size < off) return;  // ~27.7 MiB needed; fail safely if ws too small

    const size_t accB = (size_t)NNODES * DIM * 4;

    k_sniff<<<1, 64, 0, stream>>>((const unsigned*)x, (const unsigned*)ei, flags);

    hipMemsetAsync(dinv, 0, (size_t)NNODES * 4, stream);
    k_deg <<<(NEDGES + 255) / 256, 256, 0, stream>>>(ei, dinv, flags);
    k_dinv<<<(NNODES + 255) / 256, 256, 0, stream>>>(dinv);

    // ---- layer 1 ----
    k_gemm<<<NNODES, DIM, 0, stream>>>(x, 0, W1, dinv, g, flags);
    hipMemsetAsync(acc, 0, accB, stream);
    k_scatter<<<(NEDGES * (DIM / 8) + 255) / 256, 256, 0, stream>>>(ei, g, acc, flags);
    k_post1<<<(NNODES * DIM + 255) / 256, 256, 0, stream>>>(acc, g, dinv, b1, a1, flags);

    // ---- layer 2 ----
    k_gemm<<<NNODES, DIM, 0, stream>>>(g, 1, W2, dinv, g, flags);
    hipMemsetAsync(acc, 0, accB, stream);
    k_scatter<<<(NEDGES * (DIM / 8) + 255) / 256, 256, 0, stream>>>(ei, g, acc, flags);
    k_final<<<(NNODES * DIM + 255) / 256, 256, 0, stream>>>(acc, g, dinv, b2, d_out, flags);
}

// Round 3
// 399.144 us; speedup vs baseline: 11.2071x; 11.2071x over previous
//
#include <hip/hip_runtime.h>
#include <hip/hip_bf16.h>

// N=50000 nodes, E=800000 edges, D=96 (in = hidden = out)
#define NNODES 50000
#define NEDGES 800000
#define DIM    96
#define SCAN_B 256
#define NB     ((NNODES + SCAN_B - 1) / SCAN_B)   // 196 scan blocks

// flags[0] = 1 if float tensors are bf16, 0 if f32
// flags[1] = 1 if edge_index is int64, 0 if int32
__device__ __forceinline__ float loadF(const void* p, long i, int isbf) {
    return isbf ? __bfloat162float(((const __hip_bfloat16*)p)[i])
                : ((const float*)p)[i];
}
__device__ __forceinline__ int clampN(int v) {
    return v < 0 ? 0 : (v >= NNODES ? NNODES - 1 : v);
}

// single wave: sniff x's float dtype and edge_index's int width
__global__ void k_sniff(const unsigned* __restrict__ xw,
                        const unsigned* __restrict__ ew,
                        int* __restrict__ flags) {
    int lane = threadIdx.x;
    int bad = 0, nz = 0;
    for (int r = 0; r < 4; ++r) {
        unsigned w  = xw[lane + 64 * r];
        unsigned lo = w & 0xffffu;
        unsigned ex = (lo >> 7) & 0xffu;
        if (!(lo == 0u || (ex >= 90u && ex <= 145u))) bad++;
        unsigned o = ew[2 * (lane + 64 * r) + 1];
        if (o != 0u) nz++;
    }
    for (int off = 32; off; off >>= 1) {
        bad += __shfl_down(bad, off);
        nz  += __shfl_down(nz,  off);
    }
    if (lane == 0) {
        flags[0] = (bad <= 32) ? 1 : 0;
        flags[1] = (nz  <  4) ? 1 : 0;
    }
}

// cnt[dst]++ per edge (int counting sort, also yields degrees)
__global__ void k_count(const int* __restrict__ w, int* __restrict__ cnt,
                        const int* __restrict__ flags) {
    int e = blockIdx.x * blockDim.x + threadIdx.x;
    if (e >= NEDGES) return;
    int d = flags[1] ? w[2 * (NEDGES + e)] : w[NEDGES + e];
    atomicAdd(&cnt[clampN(d)], 1);
}

__global__ void k_dinv(const int* __restrict__ cnt, float* __restrict__ dinv) {
    int i = blockIdx.x * blockDim.x + threadIdx.x;
    if (i < NNODES) dinv[i] = rsqrtf((float)cnt[i] + 1.0f);  // +1 self loop
}

// exclusive scan of cnt -> rowptr (3-kernel scan)
__global__ void k_scan1(const int* __restrict__ cnt, int* __restrict__ rowptr,
                        int* __restrict__ bsum) {
    __shared__ int s[SCAN_B];
    int i = blockIdx.x * SCAN_B + threadIdx.x;
    int v = (i < NNODES) ? cnt[i] : 0;
    s[threadIdx.x] = v;
    __syncthreads();
    for (int off = 1; off < SCAN_B; off <<= 1) {
        int t = (threadIdx.x >= off) ? s[threadIdx.x - off] : 0;
        __syncthreads();
        s[threadIdx.x] += t;
        __syncthreads();
    }
    if (i < NNODES) rowptr[i] = s[threadIdx.x] - v;   // exclusive within block
    if (threadIdx.x == SCAN_B - 1) bsum[blockIdx.x] = s[SCAN_B - 1];
}

__global__ void k_scan2(int* __restrict__ bsum) {       // 1 block of 256
    __shared__ int s[SCAN_B];
    int v = (threadIdx.x < NB) ? bsum[threadIdx.x] : 0;
    s[threadIdx.x] = v;
    __syncthreads();
    for (int off = 1; off < SCAN_B; off <<= 1) {
        int t = (threadIdx.x >= off) ? s[threadIdx.x - off] : 0;
        __syncthreads();
        s[threadIdx.x] += t;
        __syncthreads();
    }
    if (threadIdx.x < NB) bsum[threadIdx.x] = s[threadIdx.x] - v;  // exclusive
}

__global__ void k_scan3(int* __restrict__ rowptr, const int* __restrict__ bsum) {
    int i = blockIdx.x * SCAN_B + threadIdx.x;
    if (i < NNODES) rowptr[i] += bsum[blockIdx.x];
    if (i == 0) rowptr[NNODES] = NEDGES;
}

// scatter edges into CSR: col[rowptr[dst] + cur[dst]++] = src
__global__ void k_fill(const int* __restrict__ w, const int* __restrict__ rowptr,
                       int* __restrict__ cur, int* __restrict__ col,
                       const int* __restrict__ flags) {
    int e = blockIdx.x * blockDim.x + threadIdx.x;
    if (e >= NEDGES) return;
    int is64 = flags[1];
    int s = is64 ? w[2 * e]            : w[e];
    int d = is64 ? w[2 * (NEDGES + e)] : w[NEDGES + e];
    s = clampN(s); d = clampN(d);
    int pos = rowptr[d] + atomicAdd(&cur[d], 1);
    col[pos] = s;
}

// g[row,j] = bf16( dinv[row] * sum_k X[row,k]*W[k,j] ); block=96, grid=N
__global__ void k_gemm(const void* __restrict__ X, int x_force_bf16,
                       const void* __restrict__ W,
                       const float* __restrict__ dinv,
                       __hip_bfloat16* __restrict__ g,
                       const int* __restrict__ flags) {
    __shared__ float xs[DIM];
    const int row = blockIdx.x;
    const int j   = threadIdx.x;
    const int fbf = flags[0];
    xs[j] = loadF(X, (long)row * DIM + j, x_force_bf16 ? 1 : fbf);
    __syncthreads();
    float acc = 0.f;
    if (fbf) {
        const __hip_bfloat16* Wb = (const __hip_bfloat16*)W;
#pragma unroll 8
        for (int k = 0; k < DIM; ++k)
            acc += xs[k] * __bfloat162float(Wb[k * DIM + j]);
    } else {
        const float* Wf = (const float*)W;
#pragma unroll 8
        for (int k = 0; k < DIM; ++k)
            acc += xs[k] * Wf[k * DIM + j];
    }
    g[(long)row * DIM + j] = __float2bfloat16(acc * dinv[row]);
}

// fused aggregate + epilogue: one 96-thread block per destination row.
// out_row = dinv[row] * (sum_{src in N(row)} g[src] + g[row]) + b  [; PReLU]
__global__ void k_aggr(const __hip_bfloat16* __restrict__ g,
                       const int* __restrict__ rowptr,
                       const int* __restrict__ col,
                       const float* __restrict__ dinv,
                       const void* __restrict__ b,
                       const void* __restrict__ a1,
                       void* __restrict__ out,
                       const int* __restrict__ flags, int prelu) {
    __shared__ int sc[DIM];
    const int row = blockIdx.x;
    const int j   = threadIdx.x;
    const int fbf = flags[0];
    float acc = __bfloat162float(g[(size_t)row * DIM + j]);   // self loop
    const int p0 = rowptr[row], p1 = rowptr[row + 1];
    for (int base = p0; base < p1; base += DIM) {
        int m = p1 - base; if (m > DIM) m = DIM;
        __syncthreads();
        if (j < m) sc[j] = col[base + j];
        __syncthreads();
        for (int i = 0; i < m; ++i)                            // independent loads
            acc += __bfloat162float(g[(size_t)sc[i] * DIM + j]);
    }
    float val = dinv[row] * acc + loadF(b, j, fbf);
    if (prelu) {
        float a = loadF(a1, 0, fbf);
        val = val > 0.f ? val : a * val;
        ((__hip_bfloat16*)out)[(size_t)row * DIM + j] = __float2bfloat16(val);
    } else {
        if (fbf) ((__hip_bfloat16*)out)[(size_t)row * DIM + j] = __float2bfloat16(val);
        else     ((float*)out)[(size_t)row * DIM + j] = val;
    }
}

extern "C" void kernel_launch(void* const* d_in, const int* in_sizes, int n_in,
                              void* d_out, int out_size, void* d_ws, size_t ws_size,
                              hipStream_t stream) {
    const void* x  = d_in[0];
    const int*  ei = (const int*)d_in[1];
    const void* W1 = d_in[2];
    const void* b1 = d_in[3];
    const void* a1 = d_in[4];
    const void* W2 = d_in[5];
    const void* b2 = d_in[6];

    size_t off = 0;
    auto alloc = [&](size_t bytes) { size_t p = off; off = (off + bytes + 255) & ~(size_t)255; return p; };
    char* ws = (char*)d_ws;
    int*            flags  = (int*)           (ws + alloc(1024));
    float*          dinv   = (float*)         (ws + alloc((size_t)NNODES * 4));
    int*            cnt    = (int*)           (ws + alloc((size_t)NNODES * 4));
    int*            cur    = (int*)           (ws + alloc((size_t)NNODES * 4));
    int*            rowptr = (int*)           (ws + alloc(((size_t)NNODES + 1) * 4));
    int*            bsum   = (int*)           (ws + alloc((size_t)NB * 4));
    int*            col    = (int*)           (ws + alloc((size_t)NEDGES * 4));
    __hip_bfloat16* g      = (__hip_bfloat16*)(ws + alloc((size_t)NNODES * DIM * 2));
    __hip_bfloat16* g2     = (__hip_bfloat16*)(ws + alloc((size_t)NNODES * DIM * 2));
    if (ws_size < off) return;   // ~23.4 MiB

    k_sniff<<<1, 64, 0, stream>>>((const unsigned*)x, (const unsigned*)ei, flags);

    // ---- CSR build (counting sort by dst) ----
    hipMemsetAsync(cnt, 0, (size_t)NNODES * 4, stream);
    hipMemsetAsync(cur, 0, (size_t)NNODES * 4, stream);
    k_count<<<(NEDGES + 255) / 256, 256, 0, stream>>>(ei, cnt, flags);
    k_dinv <<<(NNODES + 255) / 256, 256, 0, stream>>>(cnt, dinv);
    k_scan1<<<NB, SCAN_B, 0, stream>>>(cnt, rowptr, bsum);
    k_scan2<<<1, SCAN_B, 0, stream>>>(bsum);
    k_scan3<<<NB, SCAN_B, 0, stream>>>(rowptr, bsum);
    k_fill <<<(NEDGES + 255) / 256, 256, 0, stream>>>(ei, rowptr, cur, col, flags);

    // ---- layer 1 ----
    k_gemm<<<NNODES, DIM, 0, stream>>>(x, 0, W1, dinv, g, flags);
    k_aggr<<<NNODES, DIM, 0, stream>>>(g, rowptr, col, dinv, b1, a1, g2, flags, 1);

    // ---- layer 2 ----
    k_gemm<<<NNODES, DIM, 0, stream>>>(g2, 1, W2, dinv, g, flags);
    k_aggr<<<NNODES, DIM, 0, stream>>>(g, rowptr, col, dinv, b2, a1, d_out, flags, 0);
}

// Round 4
// 305.171 us; speedup vs baseline: 14.6582x; 1.3079x over previous
//
#include <hip/hip_runtime.h>
#include <hip/hip_bf16.h>

// N=50000 nodes, E=800000 edges, D=96 (in = hidden = out)
#define NNODES 50000
#define NEDGES 800000
#define DIM    96
#define SCAN_B 256
#define NB     ((NNODES + SCAN_B - 1) / SCAN_B)   // 196 scan blocks
#define TM     64                                  // rows per GEMM block
#define XPAD   104                                 // LDS row stride (bf16 elems), 16B-aligned, breaks bank clustering

typedef __attribute__((ext_vector_type(8))) short   short8;   // 8 bf16 = 4 VGPRs
typedef __attribute__((ext_vector_type(4))) float   float4v;  // MFMA acc

// flags[0] = 1 if float tensors are bf16, 0 if f32
// flags[1] = 1 if edge_index is int64, 0 if int32
__device__ __forceinline__ float loadF(const void* p, long i, int isbf) {
    return isbf ? __bfloat162float(((const __hip_bfloat16*)p)[i])
                : ((const float*)p)[i];
}
__device__ __forceinline__ int clampN(int v) {
    return v < 0 ? 0 : (v >= NNODES ? NNODES - 1 : v);
}

// single wave: sniff x's float dtype and edge_index's int width
__global__ void k_sniff(const unsigned* __restrict__ xw,
                        const unsigned* __restrict__ ew,
                        int* __restrict__ flags) {
    int lane = threadIdx.x;
    int bad = 0, nz = 0;
    for (int r = 0; r < 4; ++r) {
        unsigned w  = xw[lane + 64 * r];
        unsigned lo = w & 0xffffu;
        unsigned ex = (lo >> 7) & 0xffu;
        if (!(lo == 0u || (ex >= 90u && ex <= 145u))) bad++;
        unsigned o = ew[2 * (lane + 64 * r) + 1];
        if (o != 0u) nz++;
    }
    for (int off = 32; off; off >>= 1) {
        bad += __shfl_down(bad, off);
        nz  += __shfl_down(nz,  off);
    }
    if (lane == 0) {
        flags[0] = (bad <= 32) ? 1 : 0;
        flags[1] = (nz  <  4) ? 1 : 0;
    }
}

// cnt[dst]++ per edge (counting sort pass 1; also yields degrees)
__global__ void k_count(const int* __restrict__ w, int* __restrict__ cnt,
                        const int* __restrict__ flags) {
    int e = blockIdx.x * blockDim.x + threadIdx.x;
    if (e >= NEDGES) return;
    int d = flags[1] ? w[2 * (NEDGES + e)] : w[NEDGES + e];
    atomicAdd(&cnt[clampN(d)], 1);
}

// exclusive scan of cnt -> rowptr; also dinv = rsqrt(cnt+1) (fused)
__global__ void k_scan1(const int* __restrict__ cnt, int* __restrict__ rowptr,
                        int* __restrict__ bsum, float* __restrict__ dinv) {
    __shared__ int s[SCAN_B];
    int i = blockIdx.x * SCAN_B + threadIdx.x;
    int v = (i < NNODES) ? cnt[i] : 0;
    if (i < NNODES) dinv[i] = rsqrtf((float)v + 1.0f);   // +1 self loop
    s[threadIdx.x] = v;
    __syncthreads();
    for (int off = 1; off < SCAN_B; off <<= 1) {
        int t = (threadIdx.x >= off) ? s[threadIdx.x - off] : 0;
        __syncthreads();
        s[threadIdx.x] += t;
        __syncthreads();
    }
    if (i < NNODES) rowptr[i] = s[threadIdx.x] - v;
    if (threadIdx.x == SCAN_B - 1) bsum[blockIdx.x] = s[SCAN_B - 1];
}

__global__ void k_scan2(int* __restrict__ bsum) {       // 1 block of 256
    __shared__ int s[SCAN_B];
    int v = (threadIdx.x < NB) ? bsum[threadIdx.x] : 0;
    s[threadIdx.x] = v;
    __syncthreads();
    for (int off = 1; off < SCAN_B; off <<= 1) {
        int t = (threadIdx.x >= off) ? s[threadIdx.x - off] : 0;
        __syncthreads();
        s[threadIdx.x] += t;
        __syncthreads();
    }
    if (threadIdx.x < NB) bsum[threadIdx.x] = s[threadIdx.x] - v;
}

__global__ void k_scan3(int* __restrict__ rowptr, const int* __restrict__ bsum) {
    int i = blockIdx.x * SCAN_B + threadIdx.x;
    if (i < NNODES) rowptr[i] += bsum[blockIdx.x];
    if (i == 0) rowptr[NNODES] = NEDGES;
}

// scatter edges into CSR: col[rowptr[dst] + cur[dst]++] = src
__global__ void k_fill(const int* __restrict__ w, const int* __restrict__ rowptr,
                       int* __restrict__ cur, int* __restrict__ col,
                       const int* __restrict__ flags) {
    int e = blockIdx.x * blockDim.x + threadIdx.x;
    if (e >= NEDGES) return;
    int is64 = flags[1];
    int s = is64 ? w[2 * e]            : w[e];
    int d = is64 ? w[2 * (NEDGES + e)] : w[NEDGES + e];
    s = clampN(s); d = clampN(d);
    int pos = rowptr[d] + atomicAdd(&cur[d], 1);
    col[pos] = s;
}

// MFMA GEMM: g[row,:] = bf16( dinv[row] * (X[row,:] @ W) )
// block = 256 (4 waves), 64 rows/block; X strip + W^T staged in LDS as bf16.
// Layouts (verified, guide §3): A[m=lane&15][k=quad*8+j]; B[k][n=lane&15] same k;
// C/D: col=lane&15, row=quad*4+reg.
__global__ __launch_bounds__(256) void k_gemm_mfma(
        const void* __restrict__ X, int x_force_bf16,
        const void* __restrict__ W,
        const float* __restrict__ dinv,
        __hip_bfloat16* __restrict__ g,
        const int* __restrict__ flags) {
    __shared__ __hip_bfloat16 Xs[TM * XPAD];     // 13.3 KB
    __shared__ __hip_bfloat16 Wt[DIM * XPAD];    // 20.0 KB  (Wt[n][k] = W[k][n])

    const int t    = threadIdx.x;
    const int fbf  = flags[0];
    const int xbf  = x_force_bf16 ? 1 : fbf;
    const int row0 = blockIdx.x * TM;

    // stage W transposed (read coalesced over idx = k*96+n)
    for (int idx = t; idx < DIM * DIM; idx += 256) {
        int k = idx / DIM, n = idx - k * DIM;
        Wt[n * XPAD + k] = __float2bfloat16(loadF(W, idx, fbf));
    }
    // stage X strip (zero-fill rows past N)
    for (int idx = t; idx < TM * DIM; idx += 256) {
        int r = idx / DIM, c = idx - r * DIM;
        int gr = row0 + r;
        float v = (gr < NNODES) ? loadF(X, (long)gr * DIM + c, xbf) : 0.f;
        Xs[r * XPAD + c] = __float2bfloat16(v);
    }
    __syncthreads();

    const int wave = t >> 6;
    const int lane = t & 63;
    const int m    = lane & 15;
    const int quad = lane >> 4;

    // A fragments for this wave's 16-row strip, all 3 K-chunks
    const short* xsp = (const short*)Xs;
    short8 a[3];
#pragma unroll
    for (int kt = 0; kt < 3; ++kt)
        a[kt] = *(const short8*)(xsp + (wave * 16 + m) * XPAD + kt * 32 + quad * 8);

    // per-lane output rows and their dinv
    float dv[4];
#pragma unroll
    for (int r2 = 0; r2 < 4; ++r2) {
        int gr = row0 + wave * 16 + quad * 4 + r2;
        dv[r2] = (gr < NNODES) ? dinv[gr] : 0.f;
    }

    const short* wtp = (const short*)Wt;
#pragma unroll
    for (int nt = 0; nt < 6; ++nt) {
        float4v acc = {0.f, 0.f, 0.f, 0.f};
#pragma unroll
        for (int kt = 0; kt < 3; ++kt) {
            short8 b = *(const short8*)(wtp + (nt * 16 + m) * XPAD + kt * 32 + quad * 8);
            acc = __builtin_amdgcn_mfma_f32_16x16x32_bf16(a[kt], b, acc, 0, 0, 0);
        }
#pragma unroll
        for (int r2 = 0; r2 < 4; ++r2) {
            int gr = row0 + wave * 16 + quad * 4 + r2;
            if (gr < NNODES)
                g[(size_t)gr * DIM + nt * 16 + m] = __float2bfloat16(acc[r2] * dv[r2]);
        }
    }
}

// fused aggregate + epilogue: one 96-thread block per destination row.
// out_row = dinv[row] * (sum_{src} g[src] + g[row]) + b  [; PReLU]
// col[] reads are block-uniform (scalar); g loads batched 8-wide for MLP.
__global__ void k_aggr(const __hip_bfloat16* __restrict__ g,
                       const int* __restrict__ rowptr,
                       const int* __restrict__ col,
                       const float* __restrict__ dinv,
                       const void* __restrict__ b,
                       const void* __restrict__ a1,
                       void* __restrict__ out,
                       const int* __restrict__ flags, int prelu) {
    const int row = blockIdx.x;
    const int j   = threadIdx.x;
    const int fbf = flags[0];
    float acc = __bfloat162float(g[(size_t)row * DIM + j]);   // self loop
    const int p0 = rowptr[row], p1 = rowptr[row + 1];
    int i = p0;
    for (; i + 8 <= p1; i += 8) {
        int s0 = col[i+0], s1 = col[i+1], s2 = col[i+2], s3 = col[i+3];
        int s4 = col[i+4], s5 = col[i+5], s6 = col[i+6], s7 = col[i+7];
        float v0 = __bfloat162float(g[(size_t)s0 * DIM + j]);
        float v1 = __bfloat162float(g[(size_t)s1 * DIM + j]);
        float v2 = __bfloat162float(g[(size_t)s2 * DIM + j]);
        float v3 = __bfloat162float(g[(size_t)s3 * DIM + j]);
        float v4 = __bfloat162float(g[(size_t)s4 * DIM + j]);
        float v5 = __bfloat162float(g[(size_t)s5 * DIM + j]);
        float v6 = __bfloat162float(g[(size_t)s6 * DIM + j]);
        float v7 = __bfloat162float(g[(size_t)s7 * DIM + j]);
        acc += ((v0 + v1) + (v2 + v3)) + ((v4 + v5) + (v6 + v7));
    }
    for (; i + 4 <= p1; i += 4) {
        int s0 = col[i+0], s1 = col[i+1], s2 = col[i+2], s3 = col[i+3];
        float v0 = __bfloat162float(g[(size_t)s0 * DIM + j]);
        float v1 = __bfloat162float(g[(size_t)s1 * DIM + j]);
        float v2 = __bfloat162float(g[(size_t)s2 * DIM + j]);
        float v3 = __bfloat162float(g[(size_t)s3 * DIM + j]);
        acc += (v0 + v1) + (v2 + v3);
    }
    for (; i < p1; ++i)
        acc += __bfloat162float(g[(size_t)col[i] * DIM + j]);

    float val = dinv[row] * acc + loadF(b, j, fbf);
    if (prelu) {
        float a = loadF(a1, 0, fbf);
        val = val > 0.f ? val : a * val;
        ((__hip_bfloat16*)out)[(size_t)row * DIM + j] = __float2bfloat16(val);
    } else {
        if (fbf) ((__hip_bfloat16*)out)[(size_t)row * DIM + j] = __float2bfloat16(val);
        else     ((float*)out)[(size_t)row * DIM + j] = val;
    }
}

extern "C" void kernel_launch(void* const* d_in, const int* in_sizes, int n_in,
                              void* d_out, int out_size, void* d_ws, size_t ws_size,
                              hipStream_t stream) {
    const void* x  = d_in[0];
    const int*  ei = (const int*)d_in[1];
    const void* W1 = d_in[2];
    const void* b1 = d_in[3];
    const void* a1 = d_in[4];
    const void* W2 = d_in[5];
    const void* b2 = d_in[6];

    size_t off = 0;
    auto alloc = [&](size_t bytes) { size_t p = off; off = (off + bytes + 255) & ~(size_t)255; return p; };
    char* ws = (char*)d_ws;
    int*            flags  = (int*)           (ws + alloc(1024));
    float*          dinv   = (float*)         (ws + alloc((size_t)NNODES * 4));
    int*            cnt    = (int*)           (ws + alloc((size_t)NNODES * 8)); // cnt+cur contiguous
    int*            cur    = cnt + NNODES;
    int*            rowptr = (int*)           (ws + alloc(((size_t)NNODES + 1) * 4));
    int*            bsum   = (int*)           (ws + alloc((size_t)NB * 4));
    int*            col    = (int*)           (ws + alloc((size_t)NEDGES * 4));
    __hip_bfloat16* g      = (__hip_bfloat16*)(ws + alloc((size_t)NNODES * DIM * 2));
    __hip_bfloat16* g2     = (__hip_bfloat16*)(ws + alloc((size_t)NNODES * DIM * 2));
    if (ws_size < off) return;   // ~23.4 MiB

    k_sniff<<<1, 64, 0, stream>>>((const unsigned*)x, (const unsigned*)ei, flags);

    // ---- CSR build (counting sort by dst) ----
    hipMemsetAsync(cnt, 0, (size_t)NNODES * 8, stream);
    k_count<<<(NEDGES + 255) / 256, 256, 0, stream>>>(ei, cnt, flags);
    k_scan1<<<NB, SCAN_B, 0, stream>>>(cnt, rowptr, bsum, dinv);
    k_scan2<<<1, SCAN_B, 0, stream>>>(bsum);
    k_scan3<<<NB, SCAN_B, 0, stream>>>(rowptr, bsum);
    k_fill <<<(NEDGES + 255) / 256, 256, 0, stream>>>(ei, rowptr, cur, col, flags);

    const int gemm_grid = (NNODES + TM - 1) / TM;   // 782

    // ---- layer 1 ----
    k_gemm_mfma<<<gemm_grid, 256, 0, stream>>>(x, 0, W1, dinv, g, flags);
    k_aggr<<<NNODES, DIM, 0, stream>>>(g, rowptr, col, dinv, b1, a1, g2, flags, 1);

    // ---- layer 2 ----
    k_gemm_mfma<<<gemm_grid, 256, 0, stream>>>(g2, 1, W2, dinv, g, flags);
    k_aggr<<<NNODES, DIM, 0, stream>>>(g, rowptr, col, dinv, b2, a1, d_out, flags, 0);
}